// Round 8
// baseline (153.219 us; speedup 1.0000x reference)
//
#include <hip/hip_runtime.h>

#define BATCH 8192
#define LOSC  2048.0f
#define LOINV (1.0f / 2048.0f)

typedef _Float16 f16x8 __attribute__((ext_vector_type(8)));
typedef __fp16   fp16x2 __attribute__((ext_vector_type(2)));
typedef float    f32x4 __attribute__((ext_vector_type(4)));

union PK2 { fp16x2 h; unsigned u; };
union U8  { f16x8 v; unsigned u[4]; };

template<int N> struct IC { static constexpr int V = N; };

// pack two f32 -> 2 f16 via v_cvt_pkrtz (RTZ fine for hi/lo splitting)
__device__ __forceinline__ unsigned pkrtz(float a, float b) {
    PK2 p; p.h = __builtin_amdgcn_cvt_pkrtz(a, b); return p.u;
}

// Packed lo residual: f16x2{ (a-hi0)*2048, (b-hi1)*2048 } via 2 mixed FMAs.
__device__ __forceinline__ unsigned lopair(unsigned hipk, float am, float bm,
                                           float n2048) {
    unsigned d;
    asm("v_fma_mixlo_f16 %0, %1, %2, %3 op_sel:[0,0,0] op_sel_hi:[1,0,0]\n\t"
        "v_fma_mixhi_f16 %0, %1, %2, %4 op_sel:[1,0,0] op_sel_hi:[1,0,0]"
        : "=&v"(d)
        : "v"(hipk), "v"(n2048), "v"(am), "v"(bm));
    return d;
}

// lane i <-> i^8 exchange via DPP ROW_ROR:8 (xor-8 within 16-lane rows).
__device__ __forceinline__ float xor8f(float v) {
    const int r = __builtin_amdgcn_mov_dpp(__builtin_bit_cast(int, v),
                                           0x128 /*ROW_ROR:8*/, 0xf, 0xf, false);
    return __builtin_bit_cast(float, r);
}

// butterfly-sum with lane^16 / lane^32 partner via v_permlane16/32_swap.
// Opaque v_mov keeps a/b in distinct physregs (R4 self-swap bug fix).
__device__ __forceinline__ float bfly16(float g) {
    float a = g, b;
    asm volatile("v_mov_b32 %0, %1" : "=v"(b) : "v"(g));
    asm("v_permlane16_swap_b32 %0, %1" : "+v"(a), "+v"(b));
    return a + b;
}
__device__ __forceinline__ float bfly32(float g) {
    float a = g, b;
    asm volatile("v_mov_b32 %0, %1" : "=v"(b) : "v"(g));
    asm("v_permlane32_swap_b32 %0, %1" : "+v"(a), "+v"(b));
    return a + b;
}

// ---------------------------------------------------------------------------
// R8: 2-wave cooperative blocks (128 thr), 2 waves/SIMD. R3/R6/R7 plateaued
// at 88.5-91us with ~45% stall at 1 wave/SIMD — a single wave can't fill
// its own dependency bubbles. Split (not duplicate): wave w owns output
// tiles T={2w,2w+1} => half the MFMAs + half the combine/L4 work per wave.
// Couplings per step: (a) B2 chunk exchange (wave w packs exactly global
// K-chunk M=w; 32B/lane each way via double-buffered LDS), (b) scalar
// partial-g sum. 2 barriers/step. y bitwise-synced across waves (g_own +
// g_partner commutative). template<WID> keeps ALL indices compile-time.
// L1 duplicated per wave (cheap; keeps B1 local, no extra sync).
// LDS 32KB (NN buffer; first 2320 floats reused for c0/B2/g exchange).
// ---------------------------------------------------------------------------
__global__ __launch_bounds__(128, 2) void solve_kernel(
    const float* __restrict__ x, const float* __restrict__ c,
    const float* __restrict__ W1, const float* __restrict__ b1,
    const float* __restrict__ W2, const float* __restrict__ b2,
    const float* __restrict__ W3, const float* __restrict__ b3,
    const float* __restrict__ W4, float* __restrict__ out)
{
    const int tid   = threadIdx.x;
    const int wid   = tid >> 6;
    const int lane  = tid & 63;
    const int sbase = blockIdx.x * 8;
    const float n2048 = -2048.0f;

    // ---- stage all c into LDS (32 KiB) ----
    __shared__ float cs[BATCH];
    {
        const float4* cg = (const float4*)c;
        float4* cl = (float4*)cs;
        #pragma unroll
        for (int j = 0; j < BATCH / 4 / 128; ++j)
            cl[tid + j * 128] = cg[tid + j * 128];
    }
    __syncthreads();

    // ---- fused NN: 16 slots per sample (128 threads / 8 samples) ----
    float c0s;
    {
        const int gs = tid >> 4;       // sample 0..7
        const int p  = tid & 15;       // scan slot
        const int si = sbase + gs;
        const float ci = cs[si];
        const int sj0 = ((si & 3) == 0) ? (si >> 2) : -1;
        const int sj1 = ((si & 3) == 1) ? (si >> 2) : -1;
        const int sj2 = ((si & 3) == 2) ? (si >> 2) : -1;
        const int sj3 = ((si & 3) == 3) ? (si >> 2) : -1;
        const float4* cs4 = (const float4*)cs;
        float bd0 = 3e38f, bd1 = 3e38f, bd2 = 3e38f, bd3 = 3e38f;
        int   bj0 = 0,     bj1 = 0,     bj2 = 0,     bj3 = 0;
        #pragma unroll 1
        for (int big = 0; big < 8; ++big) {
            float4 vv[16];
            #pragma unroll
            for (int u = 0; u < 16; ++u)
                vv[u] = cs4[p + (big * 16 + u) * 16];
            #pragma unroll
            for (int u = 0; u < 16; ++u) {
                const int jj = p + (big * 16 + u) * 16;
                const float4 v = vv[u];
                float d0 = fabsf(ci - v.x);
                float d1 = fabsf(ci - v.y);
                float d2 = fabsf(ci - v.z);
                float d3 = fabsf(ci - v.w);
                if (jj == sj0) d0 = 3e38f;
                if (jj == sj1) d1 = 3e38f;
                if (jj == sj2) d2 = 3e38f;
                if (jj == sj3) d3 = 3e38f;
                if (d0 < bd0) { bd0 = d0; bj0 = jj; }
                if (d1 < bd1) { bd1 = d1; bj1 = jj; }
                if (d2 < bd2) { bd2 = d2; bj2 = jj; }
                if (d3 < bd3) { bd3 = d3; bj3 = jj; }
            }
        }
        float best = bd0; int bestj = bj0 * 4 + 0;
        { const int j1 = bj1 * 4 + 1; if (bd1 < best || (bd1 == best && j1 < bestj)) { best = bd1; bestj = j1; } }
        { const int j2 = bj2 * 4 + 2; if (bd2 < best || (bd2 == best && j2 < bestj)) { best = bd2; bestj = j2; } }
        { const int j3 = bj3 * 4 + 3; if (bd3 < best || (bd3 == best && j3 < bestj)) { best = bd3; bestj = j3; } }
        #pragma unroll
        for (int off = 1; off < 16; off <<= 1) {
            const float od = __shfl_xor(best, off);
            const int   oj = __shfl_xor(bestj, off);
            if (od < best || (od == best && oj < bestj)) { best = od; bestj = oj; }
        }
        const float bestc = cs[bestj];     // read BEFORE any cs write
        __syncthreads();                   // all scan reads complete
        if (p == 0) cs[gs] = bestc;        // c0buf = cs[0..7]
        __syncthreads();
        c0s = cs[lane & 7];                // sample s = (lane&15)&7 = lane&7
    }

    // ---- per-lane roles for GD ----
    const int q  = lane >> 4;
    const int cc = lane & 15;
    const bool fwd = (cc < 8);
    const int s = cc & 7;

    // ---- layer-1 constants (WID-independent): k = m*16 + q*4 + j ----
    float A1v[16], w11v[16];
    {
        const float xs = x[sbase + s];
        #pragma unroll
        for (int m = 0; m < 4; ++m)
            #pragma unroll
            for (int j = 0; j < 4; ++j) {
                const int k = m * 16 + q * 4 + j;
                w11v[m * 4 + j] = W1[k * 3 + 1];
                A1v[m * 4 + j]  = fmaf(xs, W1[k * 3 + 0],
                                       fmaf(c0s, W1[k * 3 + 2], b1[k]));
            }
    }

    // exchange regions carved from cs (disjoint from c0buf cs[0..7]):
    // xb: [par][wave][h/l][64] f16x8 at cs[16..2063]; gxb: [par][wave][64]
    // floats at cs[2064..2319].
    f16x8* xb  = (f16x8*)(cs + 16);
    float* gxb = cs + 2064;

    auto gd = [&](auto wc) {
        constexpr int WID = decltype(wc)::V;

        // ---- own W2/W3 hi+lo fragments (tiles 2*WID, 2*WID+1): 64 VGPRs ----
        f16x8 W2h[2][2], W2l[2][2], W3h[2][2], W3l[2][2];
        #pragma unroll
        for (int Tl = 0; Tl < 2; ++Tl)
            #pragma unroll
            for (int M = 0; M < 2; ++M) {
                const int off0 = ((WID * 2 + Tl) * 16 + cc) * 64 + M * 32 + q * 4;
                const int off1 = off0 + 16;
                float4 a = *(const float4*)(W2 + off0);
                float4 b = *(const float4*)(W2 + off1);
                U8 h, l;
                h.u[0] = pkrtz(a.x, a.y); h.u[1] = pkrtz(a.z, a.w);
                h.u[2] = pkrtz(b.x, b.y); h.u[3] = pkrtz(b.z, b.w);
                l.u[0] = lopair(h.u[0], a.x * LOSC, a.y * LOSC, n2048);
                l.u[1] = lopair(h.u[1], a.z * LOSC, a.w * LOSC, n2048);
                l.u[2] = lopair(h.u[2], b.x * LOSC, b.y * LOSC, n2048);
                l.u[3] = lopair(h.u[3], b.z * LOSC, b.w * LOSC, n2048);
                W2h[Tl][M] = h.v; W2l[Tl][M] = l.v;
                a = *(const float4*)(W3 + off0);
                b = *(const float4*)(W3 + off1);
                h.u[0] = pkrtz(a.x, a.y); h.u[1] = pkrtz(a.z, a.w);
                h.u[2] = pkrtz(b.x, b.y); h.u[3] = pkrtz(b.z, b.w);
                l.u[0] = lopair(h.u[0], a.x * LOSC, a.y * LOSC, n2048);
                l.u[1] = lopair(h.u[1], a.z * LOSC, a.w * LOSC, n2048);
                l.u[2] = lopair(h.u[2], b.x * LOSC, b.y * LOSC, n2048);
                l.u[3] = lopair(h.u[3], b.z * LOSC, b.w * LOSC, n2048);
                W3h[Tl][M] = h.v; W3l[Tl][M] = l.v;
            }

        // ---- own biases + W4 rows ----
        f32x4 b2q[2], b3q[2];
        const f32x4 zq = {0.f, 0.f, 0.f, 0.f};
        float w4r[8];
        #pragma unroll
        for (int Tl = 0; Tl < 2; ++Tl)
            #pragma unroll
            for (int r = 0; r < 4; ++r) {
                const int row = (WID * 2 + Tl) * 16 + q * 4 + r;
                b2q[Tl][r] = fwd ? b2[row] : 0.f;
                b3q[Tl][r] = fwd ? b3[row] : 0.f;
                w4r[Tl * 4 + r] = W4[row];
            }

        float y = 0.0f;

        #pragma unroll 1
        for (int step = 0; step < 50; ++step) {
            const int par = step & 1;
            // ---- layer 1 (full, duplicated per wave) -> B1 chunks ----
            U8 B1h[2], B1l[2];
            #pragma unroll
            for (int m = 0; m < 4; ++m) {
                float v[4];
                #pragma unroll
                for (int j = 0; j < 4; ++j) {
                    const float w = w11v[m * 4 + j];
                    const float z = fmaf(y, w, A1v[m * 4 + j]);
                    const float a = fwd ? z : w;
                    v[j] = (z > 0.f) ? a : 0.f;
                }
                const unsigned h0 = pkrtz(v[0], v[1]);
                const unsigned h1 = pkrtz(v[2], v[3]);
                const int M = m >> 1, o = (m & 1) * 2;
                B1h[M].u[o]     = h0;
                B1h[M].u[o + 1] = h1;
                B1l[M].u[o]     = lopair(h0, v[0] * LOSC, v[1] * LOSC, n2048);
                B1l[M].u[o + 1] = lopair(h1, v[2] * LOSC, v[3] * LOSC, n2048);
            }
            // ---- layer 2: own tiles, 12 MFMA ----
            f32x4 ZH[2], ZL[2];
            #pragma unroll
            for (int Tl = 0; Tl < 2; ++Tl) {
                f32x4 aH = __builtin_amdgcn_mfma_f32_16x16x32_f16(W2h[Tl][0], B1h[0].v, b2q[Tl], 0, 0, 0);
                f32x4 aL = __builtin_amdgcn_mfma_f32_16x16x32_f16(W2h[Tl][0], B1l[0].v, zq, 0, 0, 0);
                aL = __builtin_amdgcn_mfma_f32_16x16x32_f16(W2l[Tl][0], B1h[0].v, aL, 0, 0, 0);
                aH = __builtin_amdgcn_mfma_f32_16x16x32_f16(W2h[Tl][1], B1h[1].v, aH, 0, 0, 0);
                aL = __builtin_amdgcn_mfma_f32_16x16x32_f16(W2h[Tl][1], B1l[1].v, aL, 0, 0, 0);
                aL = __builtin_amdgcn_mfma_f32_16x16x32_f16(W2l[Tl][1], B1h[1].v, aL, 0, 0, 0);
                ZH[Tl] = aH; ZL[Tl] = aL;
            }
            // ---- combine + mask + pack own B2 chunk (global M = WID) ----
            U8 oh, ol;
            {
                float zv[8], rv[8];
                #pragma unroll
                for (int i = 0; i < 8; ++i)
                    zv[i] = fmaf(ZL[i >> 2][i & 3], LOINV, ZH[i >> 2][i & 3]);
                #pragma unroll
                for (int i = 0; i < 8; ++i)
                    rv[i] = xor8f(zv[i]);
                #pragma unroll
                for (int Tl = 0; Tl < 2; ++Tl) {
                    float v[4];
                    #pragma unroll
                    for (int r = 0; r < 4; ++r) {
                        const float z = zv[Tl * 4 + r];
                        const float gate = fwd ? z : rv[Tl * 4 + r];
                        v[r] = (gate > 0.f) ? z : 0.f;
                    }
                    const unsigned h0 = pkrtz(v[0], v[1]);
                    const unsigned h1 = pkrtz(v[2], v[3]);
                    oh.u[Tl * 2]     = h0;
                    oh.u[Tl * 2 + 1] = h1;
                    ol.u[Tl * 2]     = lopair(h0, v[0] * LOSC, v[1] * LOSC, n2048);
                    ol.u[Tl * 2 + 1] = lopair(h1, v[2] * LOSC, v[3] * LOSC, n2048);
                }
            }
            // ---- exchange B2 chunks (double-buffered by parity) ----
            xb[((par * 2 + WID) * 2 + 0) * 64 + lane] = oh.v;
            xb[((par * 2 + WID) * 2 + 1) * 64 + lane] = ol.v;
            __syncthreads();
            const f16x8 ph = xb[((par * 2 + (WID ^ 1)) * 2 + 0) * 64 + lane];
            const f16x8 pl = xb[((par * 2 + (WID ^ 1)) * 2 + 1) * 64 + lane];
            f16x8 B2h0, B2l0, B2h1, B2l1;   // global chunk order, all static
            if constexpr (WID == 0) { B2h0 = oh.v; B2l0 = ol.v; B2h1 = ph; B2l1 = pl; }
            else                    { B2h0 = ph;   B2l0 = pl;   B2h1 = oh.v; B2l1 = ol.v; }
            // ---- layer 3: own tiles, 12 MFMA ----
            #pragma unroll
            for (int Tl = 0; Tl < 2; ++Tl) {
                f32x4 aH = __builtin_amdgcn_mfma_f32_16x16x32_f16(W3h[Tl][0], B2h0, b3q[Tl], 0, 0, 0);
                f32x4 aL = __builtin_amdgcn_mfma_f32_16x16x32_f16(W3h[Tl][0], B2l0, zq, 0, 0, 0);
                aL = __builtin_amdgcn_mfma_f32_16x16x32_f16(W3l[Tl][0], B2h0, aL, 0, 0, 0);
                aH = __builtin_amdgcn_mfma_f32_16x16x32_f16(W3h[Tl][1], B2h1, aH, 0, 0, 0);
                aL = __builtin_amdgcn_mfma_f32_16x16x32_f16(W3h[Tl][1], B2l1, aL, 0, 0, 0);
                aL = __builtin_amdgcn_mfma_f32_16x16x32_f16(W3l[Tl][1], B2h1, aL, 0, 0, 0);
                ZH[Tl] = aH; ZL[Tl] = aL;
            }
            // ---- layer 4: partial over own 8 rows, 2 parallel chains ----
            float gp;
            {
                float zv[8], rv[8];
                #pragma unroll
                for (int i = 0; i < 8; ++i)
                    zv[i] = fmaf(ZL[i >> 2][i & 3], LOINV, ZH[i >> 2][i & 3]);
                #pragma unroll
                for (int i = 0; i < 8; ++i)
                    rv[i] = xor8f(zv[i]);
                float s0 = 0.f, s1 = 0.f;
                #pragma unroll
                for (int r = 0; r < 4; ++r) {
                    const float ga = fwd ? zv[r] : rv[r];
                    const float va = fwd ? rv[r] : zv[r];
                    s0 = fmaf(w4r[r], (ga > 0.f) ? va : 0.f, s0);
                    const float gb = fwd ? zv[4 + r] : rv[4 + r];
                    const float vb = fwd ? rv[4 + r] : zv[4 + r];
                    s1 = fmaf(w4r[4 + r], (gb > 0.f) ? vb : 0.f, s1);
                }
                gp = s0 + s1;
                gp = bfly16(gp);   // sum over q (lane^16)
                gp = bfly32(gp);   // sum over q (lane^32)
            }
            // ---- cross-wave g sum (double-buffered) ----
            gxb[(par * 2 + WID) * 64 + lane] = gp;
            __syncthreads();
            float g = gp + gxb[(par * 2 + (WID ^ 1)) * 64 + lane];
            const float gx = xor8f(g);
            g = fwd ? gx : g;
            y -= 0.1f * g;
        }
        if (WID == 0 && lane < 8) out[sbase + lane] = y;
    };

    if (wid == 0) gd(IC<0>{}); else gd(IC<1>{});
}

extern "C" void kernel_launch(void* const* d_in, const int* in_sizes, int n_in,
                              void* d_out, int out_size, void* d_ws, size_t ws_size,
                              hipStream_t stream) {
    const float* x  = (const float*)d_in[0];
    const float* c  = (const float*)d_in[1];
    const float* W1 = (const float*)d_in[2];
    const float* b1 = (const float*)d_in[3];
    const float* W2 = (const float*)d_in[4];
    const float* b2 = (const float*)d_in[5];
    const float* W3 = (const float*)d_in[6];
    const float* b3 = (const float*)d_in[7];
    const float* W4 = (const float*)d_in[8];
    // d_in[9] = b4: unused (only grad wrt y is needed, b4 drops out)
    float* out = (float*)d_out;

    solve_kernel<<<BATCH / 8, 128, 0, stream>>>(x, c, W1, b1, W2, b2, W3, b3, W4, out);
}

// Round 10
// 145.646 us; speedup vs baseline: 1.0520x; 1.0520x over previous
//
#include <hip/hip_runtime.h>

#define BATCH 8192
#define LOSC  2048.0f
#define LOINV (1.0f / 2048.0f)

typedef _Float16 f16x8 __attribute__((ext_vector_type(8)));
typedef __fp16   fp16x2 __attribute__((ext_vector_type(2)));
typedef float    f32x4 __attribute__((ext_vector_type(4)));

union PK2 { fp16x2 h; unsigned u; };
union U8  { f16x8 v; unsigned u[4]; };

// pack two f32 -> 2 f16 via v_cvt_pkrtz (RTZ is fine for hi/lo splitting:
// any hi with |v-hi| <= ulp works; lo carries the remainder, scaled 2^11)
__device__ __forceinline__ unsigned pkrtz(float a, float b) {
    PK2 p; p.h = __builtin_amdgcn_cvt_pkrtz(a, b); return p.u;
}

// Packed lo residual in 2 instrs/pair: f16x2{ (a-hi0)*2048, (b-hi1)*2048 }
// computed as fma(hi, -2048, v*2048) per half via v_fma_mixlo/hi_f16.
// Intermediate is f32-exact (v-hi Sterbenz-exact, *2048 exact).
// NOTE (R9 lesson): BOTH rails are accuracy-load-bearing. g depends on fwd
// activations only through relu gates; dropping either residual rail gives
// ~5e-4 z-error -> gate flips -> O(0.1) y corruption (measured 0.127).
__device__ __forceinline__ unsigned lopair(unsigned hipk, float am, float bm,
                                           float n2048) {
    unsigned d;
    asm("v_fma_mixlo_f16 %0, %1, %2, %3 op_sel:[0,0,0] op_sel_hi:[1,0,0]\n\t"
        "v_fma_mixhi_f16 %0, %1, %2, %4 op_sel:[1,0,0] op_sel_hi:[1,0,0]"
        : "=&v"(d)
        : "v"(hipk), "v"(n2048), "v"(am), "v"(bm));
    return d;
}

// lane i <-> i^8 exchange via DPP ROW_ROR:8 (xor-8 within 16-lane rows).
__device__ __forceinline__ float xor8f(float v) {
    const int r = __builtin_amdgcn_mov_dpp(__builtin_bit_cast(int, v),
                                           0x128 /*ROW_ROR:8*/, 0xf, 0xf, false);
    return __builtin_bit_cast(float, r);
}

// butterfly-sum with lane^16 / lane^32 partner via v_permlane16/32_swap.
// Opaque v_mov keeps a/b in distinct physregs (R4 self-swap bug fix; HW-
// verified correct in R6/R8). a+b == g + shfl_xor(g,N) bitwise. Pure VALU —
// removes the last DS-pipe ops from the y-serial chain.
__device__ __forceinline__ float bfly16(float g) {
    float a = g, b;
    asm volatile("v_mov_b32 %0, %1" : "=v"(b) : "v"(g));
    asm("v_permlane16_swap_b32 %0, %1" : "+v"(a), "+v"(b));
    return a + b;
}
__device__ __forceinline__ float bfly32(float g) {
    float a = g, b;
    asm volatile("v_mov_b32 %0, %1" : "=v"(b) : "v"(g));
    asm("v_permlane32_swap_b32 %0, %1" : "+v"(a), "+v"(b));
    return a + b;
}

// ---------------------------------------------------------------------------
// Fused kernel: NN prologue (exact |dx| scan, first-index argmin, self
// excluded) + 50-step GD solve. 8 samples/wave, 1024 blocks x 1 wave.
//
// FINAL configuration = R3 structure (fastest measured: 88.5us) + bfly tail.
// Closed levers (all measured): MFMA shape swap (null), ballot/SALU gates
// (-1.4us), LDS-resident weights (-2.8us), 2-wave cooperative split (-9us),
// activation/weight precision drop (accuracy wall: gate flips), occupancy
// duplication (prior session). Kernel is serial-latency-bound at 1 wave/SIMD
// (HBM 0.07%, MfmaUtil ~18%, VALU ~55%, rest dependency stall).
// K=32 MFMA; zero-shfl inter-layer transform; B cols = [8 fwd | 8 tangent];
// masks via DPP xor-8; biases ride in as MFMA C-operands.
// ---------------------------------------------------------------------------
__global__ __launch_bounds__(64, 1) void solve_kernel(
    const float* __restrict__ x, const float* __restrict__ c,
    const float* __restrict__ W1, const float* __restrict__ b1,
    const float* __restrict__ W2, const float* __restrict__ b2,
    const float* __restrict__ W3, const float* __restrict__ b3,
    const float* __restrict__ W4, float* __restrict__ out)
{
    const int lane  = threadIdx.x & 63;
    const int sbase = blockIdx.x * 8;
    const float n2048 = -2048.0f;

    // ---- stage all c into LDS (32 KiB) ----
    __shared__ float cs[BATCH];
    {
        const float4* cg = (const float4*)c;
        float4* cl = (float4*)cs;
        #pragma unroll
        for (int j = 0; j < BATCH / 4 / 64; ++j)
            cl[lane + j * 64] = cg[lane + j * 64];
    }
    __syncthreads();

    // ---- fused NN: 8 lanes per sample scan 2048 float4 each ----
    // Two-phase body: 16 ds_read_b128 in flight, then process.
    float c0s;
    {
        const int g  = lane >> 3;
        const int p  = lane & 7;
        const int si = sbase + g;
        const float ci = cs[si];
        const int sj0 = ((si & 3) == 0) ? (si >> 2) : -1;
        const int sj1 = ((si & 3) == 1) ? (si >> 2) : -1;
        const int sj2 = ((si & 3) == 2) ? (si >> 2) : -1;
        const int sj3 = ((si & 3) == 3) ? (si >> 2) : -1;
        const float4* cs4 = (const float4*)cs;
        float bd0 = 3e38f, bd1 = 3e38f, bd2 = 3e38f, bd3 = 3e38f;
        int   bj0 = 0,     bj1 = 0,     bj2 = 0,     bj3 = 0;
        #pragma unroll 1
        for (int big = 0; big < 16; ++big) {
            float4 vv[16];
            #pragma unroll
            for (int u = 0; u < 16; ++u)
                vv[u] = cs4[p + (big * 16 + u) * 8];
            #pragma unroll
            for (int u = 0; u < 16; ++u) {
                const int jj = p + (big * 16 + u) * 8;
                const float4 v = vv[u];
                float d0 = fabsf(ci - v.x);
                float d1 = fabsf(ci - v.y);
                float d2 = fabsf(ci - v.z);
                float d3 = fabsf(ci - v.w);
                if (jj == sj0) d0 = 3e38f;
                if (jj == sj1) d1 = 3e38f;
                if (jj == sj2) d2 = 3e38f;
                if (jj == sj3) d3 = 3e38f;
                if (d0 < bd0) { bd0 = d0; bj0 = jj; }
                if (d1 < bd1) { bd1 = d1; bj1 = jj; }
                if (d2 < bd2) { bd2 = d2; bj2 = jj; }
                if (d3 < bd3) { bd3 = d3; bj3 = jj; }
            }
        }
        float best = bd0; int bestj = bj0 * 4 + 0;
        { const int j1 = bj1 * 4 + 1; if (bd1 < best || (bd1 == best && j1 < bestj)) { best = bd1; bestj = j1; } }
        { const int j2 = bj2 * 4 + 2; if (bd2 < best || (bd2 == best && j2 < bestj)) { best = bd2; bestj = j2; } }
        { const int j3 = bj3 * 4 + 3; if (bd3 < best || (bd3 == best && j3 < bestj)) { best = bd3; bestj = j3; } }
        #pragma unroll
        for (int off = 1; off < 8; off <<= 1) {
            const float od = __shfl_xor(best, off);
            const int   oj = __shfl_xor(bestj, off);
            if (od < best || (od == best && oj < bestj)) { best = od; bestj = oj; }
        }
        const float bestc = cs[bestj];
        c0s = __shfl(bestc, (lane & 7) << 3);
    }

    // ---- GD solve ----
    const int q  = lane >> 4;
    const int cc = lane & 15;
    const bool fwd = (cc < 8);
    const int s = cc & 7;

    // ---- W2/W3 hi+lo fragments (K=32 chunks), all in registers ----
    f16x8 W2h[4][2], W2l[4][2], W3h[4][2], W3l[4][2];
    #pragma unroll
    for (int T = 0; T < 4; ++T)
        #pragma unroll
        for (int M = 0; M < 2; ++M) {
            const int off0 = (T * 16 + cc) * 64 + M * 32 + q * 4;
            const int off1 = off0 + 16;
            float4 a = *(const float4*)(W2 + off0);
            float4 b = *(const float4*)(W2 + off1);
            U8 h, l;
            h.u[0] = pkrtz(a.x, a.y); h.u[1] = pkrtz(a.z, a.w);
            h.u[2] = pkrtz(b.x, b.y); h.u[3] = pkrtz(b.z, b.w);
            l.u[0] = lopair(h.u[0], a.x * LOSC, a.y * LOSC, n2048);
            l.u[1] = lopair(h.u[1], a.z * LOSC, a.w * LOSC, n2048);
            l.u[2] = lopair(h.u[2], b.x * LOSC, b.y * LOSC, n2048);
            l.u[3] = lopair(h.u[3], b.z * LOSC, b.w * LOSC, n2048);
            W2h[T][M] = h.v; W2l[T][M] = l.v;
            a = *(const float4*)(W3 + off0);
            b = *(const float4*)(W3 + off1);
            h.u[0] = pkrtz(a.x, a.y); h.u[1] = pkrtz(a.z, a.w);
            h.u[2] = pkrtz(b.x, b.y); h.u[3] = pkrtz(b.z, b.w);
            l.u[0] = lopair(h.u[0], a.x * LOSC, a.y * LOSC, n2048);
            l.u[1] = lopair(h.u[1], a.z * LOSC, a.w * LOSC, n2048);
            l.u[2] = lopair(h.u[2], b.x * LOSC, b.y * LOSC, n2048);
            l.u[3] = lopair(h.u[3], b.z * LOSC, b.w * LOSC, n2048);
            W3h[T][M] = h.v; W3l[T][M] = l.v;
        }

    // ---- biases as f32x4 (direct MFMA C-operands) + W4 rows ----
    f32x4 b2q[4], b3q[4];
    const f32x4 zq = {0.f, 0.f, 0.f, 0.f};
    float w4r[16];
    #pragma unroll
    for (int T = 0; T < 4; ++T)
        #pragma unroll
        for (int r = 0; r < 4; ++r) {
            const int row = T * 16 + q * 4 + r;
            b2q[T][r] = fwd ? b2[row] : 0.f;
            b3q[T][r] = fwd ? b3[row] : 0.f;
            w4r[T * 4 + r] = W4[row];
        }

    // ---- layer-1 constants: logical k = m*16 + q*4 + j ----
    float A1v[16], w11v[16];
    {
        const float xs = x[sbase + s];
        #pragma unroll
        for (int m = 0; m < 4; ++m)
            #pragma unroll
            for (int j = 0; j < 4; ++j) {
                const int k = m * 16 + q * 4 + j;
                w11v[m * 4 + j] = W1[k * 3 + 1];
                A1v[m * 4 + j]  = fmaf(xs, W1[k * 3 + 0],
                                       fmaf(c0s, W1[k * 3 + 2], b1[k]));
            }
    }

    float y = 0.0f;

    #pragma unroll 1
    for (int step = 0; step < 50; ++step) {
        // ---- layer 1 (fp32, registers) -> split B1 chunks (2 x K=32) ----
        U8 B1h[2], B1l[2];
        #pragma unroll
        for (int m = 0; m < 4; ++m) {
            float v[4];
            #pragma unroll
            for (int j = 0; j < 4; ++j) {
                const float w = w11v[m * 4 + j];
                const float z = fmaf(y, w, A1v[m * 4 + j]);
                const float a = fwd ? z : w;
                v[j] = (z > 0.f) ? a : 0.f;
            }
            const unsigned h0 = pkrtz(v[0], v[1]);
            const unsigned h1 = pkrtz(v[2], v[3]);
            const int M = m >> 1, o = (m & 1) * 2;
            B1h[M].u[o]     = h0;
            B1h[M].u[o + 1] = h1;
            B1l[M].u[o]     = lopair(h0, v[0] * LOSC, v[1] * LOSC, n2048);
            B1l[M].u[o + 1] = lopair(h1, v[2] * LOSC, v[3] * LOSC, n2048);
        }
        // ---- layer 2: split MFMA (bias rides in as C-operand) ----
        f32x4 ZH[4], ZL[4];
        #pragma unroll
        for (int T = 0; T < 4; ++T) {
            f32x4 aH = __builtin_amdgcn_mfma_f32_16x16x32_f16(W2h[T][0], B1h[0].v, b2q[T], 0, 0, 0);
            f32x4 aL = __builtin_amdgcn_mfma_f32_16x16x32_f16(W2h[T][0], B1l[0].v, zq, 0, 0, 0);
            aL = __builtin_amdgcn_mfma_f32_16x16x32_f16(W2l[T][0], B1h[0].v, aL, 0, 0, 0);
            aH = __builtin_amdgcn_mfma_f32_16x16x32_f16(W2h[T][1], B1h[1].v, aH, 0, 0, 0);
            aL = __builtin_amdgcn_mfma_f32_16x16x32_f16(W2h[T][1], B1l[1].v, aL, 0, 0, 0);
            aL = __builtin_amdgcn_mfma_f32_16x16x32_f16(W2l[T][1], B1h[1].v, aL, 0, 0, 0);
            ZH[T] = aH; ZL[T] = aL;
        }
        // ---- combine (batched DPP exchange) + mask -> B2 chunks ----
        {
            float zv[16], rv[16];
            #pragma unroll
            for (int i = 0; i < 16; ++i)
                zv[i] = fmaf(ZL[i >> 2][i & 3], LOINV, ZH[i >> 2][i & 3]);
            #pragma unroll
            for (int i = 0; i < 16; ++i)
                rv[i] = xor8f(zv[i]);            // VALU DPP, no DS pipe
            U8 B2h[2], B2l[2];
            #pragma unroll
            for (int T = 0; T < 4; ++T) {
                float v[4];
                #pragma unroll
                for (int r = 0; r < 4; ++r) {
                    const float z = zv[T * 4 + r];
                    const float gate = fwd ? z : rv[T * 4 + r];
                    v[r] = (gate > 0.f) ? z : 0.f;
                }
                const unsigned h0 = pkrtz(v[0], v[1]);
                const unsigned h1 = pkrtz(v[2], v[3]);
                const int M = T >> 1, o = (T & 1) * 2;
                B2h[M].u[o]     = h0;
                B2h[M].u[o + 1] = h1;
                B2l[M].u[o]     = lopair(h0, v[0] * LOSC, v[1] * LOSC, n2048);
                B2l[M].u[o + 1] = lopair(h1, v[2] * LOSC, v[3] * LOSC, n2048);
            }
            // ---- layer 3: split MFMA ----
            #pragma unroll
            for (int T = 0; T < 4; ++T) {
                f32x4 aH = __builtin_amdgcn_mfma_f32_16x16x32_f16(W3h[T][0], B2h[0].v, b3q[T], 0, 0, 0);
                f32x4 aL = __builtin_amdgcn_mfma_f32_16x16x32_f16(W3h[T][0], B2l[0].v, zq, 0, 0, 0);
                aL = __builtin_amdgcn_mfma_f32_16x16x32_f16(W3l[T][0], B2h[0].v, aL, 0, 0, 0);
                aH = __builtin_amdgcn_mfma_f32_16x16x32_f16(W3h[T][1], B2h[1].v, aH, 0, 0, 0);
                aL = __builtin_amdgcn_mfma_f32_16x16x32_f16(W3h[T][1], B2l[1].v, aL, 0, 0, 0);
                aL = __builtin_amdgcn_mfma_f32_16x16x32_f16(W3l[T][1], B2h[1].v, aL, 0, 0, 0);
                ZH[T] = aH; ZL[T] = aL;
            }
        }
        // ---- layer 4 (fp32): g = W4 . (1[z3>0] * dz3), 4 parallel chains ----
        {
            float zv[16], rv[16];
            #pragma unroll
            for (int i = 0; i < 16; ++i)
                zv[i] = fmaf(ZL[i >> 2][i & 3], LOINV, ZH[i >> 2][i & 3]);
            #pragma unroll
            for (int i = 0; i < 16; ++i)
                rv[i] = xor8f(zv[i]);            // VALU DPP, no DS pipe
            float s0 = 0.f, s1 = 0.f, s2 = 0.f, s3 = 0.f;
            #pragma unroll
            for (int T = 0; T < 4; ++T) {
                const int i0 = T * 4;
                const float g0 = fwd ? zv[i0 + 0] : rv[i0 + 0];
                const float g1 = fwd ? zv[i0 + 1] : rv[i0 + 1];
                const float g2 = fwd ? zv[i0 + 2] : rv[i0 + 2];
                const float g3 = fwd ? zv[i0 + 3] : rv[i0 + 3];
                const float v0 = fwd ? rv[i0 + 0] : zv[i0 + 0];
                const float v1 = fwd ? rv[i0 + 1] : zv[i0 + 1];
                const float v2 = fwd ? rv[i0 + 2] : zv[i0 + 2];
                const float v3 = fwd ? rv[i0 + 3] : zv[i0 + 3];
                s0 = fmaf(w4r[i0 + 0], (g0 > 0.f) ? v0 : 0.f, s0);
                s1 = fmaf(w4r[i0 + 1], (g1 > 0.f) ? v1 : 0.f, s1);
                s2 = fmaf(w4r[i0 + 2], (g2 > 0.f) ? v2 : 0.f, s2);
                s3 = fmaf(w4r[i0 + 3], (g3 > 0.f) ? v3 : 0.f, s3);
            }
            float g = (s0 + s1) + (s2 + s3);
            g = bfly16(g);            // + lane^16 partner (VALU permlane)
            g = bfly32(g);            // + lane^32 partner (VALU permlane)
            y -= 0.1f * g;
        }
    }
    if (lane < 8) out[sbase + lane] = y;
}

extern "C" void kernel_launch(void* const* d_in, const int* in_sizes, int n_in,
                              void* d_out, int out_size, void* d_ws, size_t ws_size,
                              hipStream_t stream) {
    const float* x  = (const float*)d_in[0];
    const float* c  = (const float*)d_in[1];
    const float* W1 = (const float*)d_in[2];
    const float* b1 = (const float*)d_in[3];
    const float* W2 = (const float*)d_in[4];
    const float* b2 = (const float*)d_in[5];
    const float* W3 = (const float*)d_in[6];
    const float* b3 = (const float*)d_in[7];
    const float* W4 = (const float*)d_in[8];
    // d_in[9] = b4: unused (only grad wrt y is needed, b4 drops out)
    float* out = (float*)d_out;

    solve_kernel<<<BATCH / 8, 64, 0, stream>>>(x, c, W1, b1, W2, b2, W3, b3, W4, out);
}